// Round 14
// baseline (1372.086 us; speedup 1.0000x reference)
//
#include <hip/hip_runtime.h>

typedef __bf16 bf16;
typedef __bf16 bf16x8 __attribute__((ext_vector_type(8)));
typedef float f32x4 __attribute__((ext_vector_type(4)));

#define MFMA16(A,B,C) __builtin_amdgcn_mfma_f32_16x16x32_bf16(A,B,C,0,0,0)
#define SCALE 0.08838834764831843f
#define NEGBIG (-1e30f)

#define AS1(p) ((__attribute__((address_space(1))) void*)(p))
#define AS3(p) ((__attribute__((address_space(3))) void*)(p))

#define BAR() do { asm volatile("" ::: "memory"); __builtin_amdgcn_s_barrier(); asm volatile("" ::: "memory"); } while (0)

// ---------------- f32 -> bf16 convert ----------------
__global__ void cvt_bf16(const float* __restrict__ src, bf16* __restrict__ dst, int n) {
    int i = (blockIdx.x * 256 + threadIdx.x) * 4;
    if (i < n) {
        float4 v = *(const float4*)(src + i);
        dst[i + 0] = (bf16)v.x; dst[i + 1] = (bf16)v.y;
        dst[i + 2] = (bf16)v.z; dst[i + 3] = (bf16)v.w;
    }
}

// ---------------- LayerNorm + pad to 4096 + bf16 ----------------
__global__ __launch_bounds__(256) void ln_kernel(const float* __restrict__ x,
                                                 const float* __restrict__ w,
                                                 const float* __restrict__ b,
                                                 bf16* __restrict__ xn) {
    int row = blockIdx.x;            // 0..65535  (b*4096 + p)
    int bb = row >> 12, p = row & 4095;
    int t = threadIdx.x;
    bf16* out = xn + ((size_t)row << 10);
    if (p >= 4000) {                 // padded row -> zeros
        uint2 z; z.x = 0u; z.y = 0u;
        *(uint2*)(out + t * 4) = z;
        return;
    }
    float4 v = *(const float4*)(x + (((size_t)bb * 4000 + p) << 10) + t * 4);
    float s = v.x + v.y + v.z + v.w;
    float s2 = v.x * v.x + v.y * v.y + v.z * v.z + v.w * v.w;
#pragma unroll
    for (int m = 1; m < 64; m <<= 1) { s += __shfl_xor(s, m); s2 += __shfl_xor(s2, m); }
    __shared__ float red[8];
    int wv = t >> 6, l = t & 63;
    if (l == 0) { red[wv] = s; red[4 + wv] = s2; }
    __syncthreads();
    s = red[0] + red[1] + red[2] + red[3];
    s2 = red[4] + red[5] + red[6] + red[7];
    float mu = s * (1.f / 1024.f);
    float var = s2 * (1.f / 1024.f) - mu * mu;
    float inv = rsqrtf(var + 1e-5f);
    float4 wv4 = *(const float4*)(w + t * 4);
    float4 bv4 = *(const float4*)(b + t * 4);
    union { bf16 h[4]; uint2 u; } o;
    o.h[0] = (bf16)((v.x - mu) * inv * wv4.x + bv4.x);
    o.h[1] = (bf16)((v.y - mu) * inv * wv4.y + bv4.y);
    o.h[2] = (bf16)((v.z - mu) * inv * wv4.z + bv4.z);
    o.h[3] = (bf16)((v.w - mu) * inv * wv4.w + bv4.w);
    *(uint2*)(out + t * 4) = o.u;
}

// ================= 256x256 8-phase GEMM (round-6 exact: 460 us qkv) ========
// C[M][N] = A[M][K] * B[N][K]^T, bf16 in. 512 thr = 8 waves (2M x 4N),
// BK=64, per-tile blocks, vmcnt(6) at P4/P8, 3-bit XOR swizzle (conflicts==0).
// EPI=0: bf16 C.  EPI=1: f32 out with row remap (4096-pad -> 4000) + bias.

__device__ __forceinline__ void stage_half(const bf16* __restrict__ src, int srow, int K,
                                           int kofs, bf16* ldsb, int w, int l) {
#pragma unroll
    for (int r = 0; r < 2; ++r) {
        int rh = (r * 8 + w) * 8 + (l >> 3);          // row within 128-row half
        int chunk = (l & 7) ^ (rh & 7);               // inverse 3-bit swizzle on source
        __builtin_amdgcn_global_load_lds(AS1(src + (size_t)(srow + rh) * K + kofs + chunk * 8),
                                         AS3(ldsb + (r * 8 + w) * 512), 16, 0, 0);
    }
}

__device__ __forceinline__ bf16x8 fragLD(const bf16* base, int row, int ks, int lk) {
    int ch = ((ks * 4 + lk) ^ (row & 7)) * 8;
    return *(const bf16x8*)(base + row * 64 + ch);
}

#define RDA(AF, base, mofs) \
    _Pragma("unroll") for (int m = 0; m < 4; ++m) \
    _Pragma("unroll") for (int ks = 0; ks < 2; ++ks) \
        AF[m][ks] = fragLD(base, rA + (mofs + m) * 16 + lrow, ks, lk);

#define RDB2(nb, base) \
    _Pragma("unroll") for (int n = 0; n < 2; ++n) \
    _Pragma("unroll") for (int ks = 0; ks < 2; ++ks) \
        bfr[(nb) + n][ks] = fragLD(base, rB + ((nb) + n) * 16 + lrow, ks, lk);

#define MM(mb, AF, nb) do { \
    __builtin_amdgcn_s_setprio(1); \
    _Pragma("unroll") for (int m = 0; m < 4; ++m) \
    _Pragma("unroll") for (int n = 0; n < 2; ++n) \
    _Pragma("unroll") for (int ks = 0; ks < 2; ++ks) \
        acc[(mb) + m][(nb) + n] = MFMA16(AF[m][ks], bfr[(nb) + n][ks], acc[(mb) + m][(nb) + n]); \
    __builtin_amdgcn_s_setprio(0); } while (0)

template <int EPI>
__global__ __launch_bounds__(512, 2) void gemm256(const bf16* __restrict__ A,
                                                  const bf16* __restrict__ B,
                                                  bf16* __restrict__ C,
                                                  float* __restrict__ Cf,
                                                  const float* __restrict__ bias,
                                                  int M, int N, int K) {
    __shared__ __align__(16) bf16 LA[2 * 16384];
    __shared__ __align__(16) bf16 LB[2 * 16384];
    const int t = threadIdx.x;
    const int w = t >> 6, l = t & 63;
    const int lrow = l & 15, lk = l >> 4;
    const int wrM = w >> 2, wn = w & 3;
    const int rA = wrM * 128, rB = wn * 64;

    const int nwg = gridDim.x, cpx = nwg >> 3;
    const int swz = ((int)blockIdx.x & 7) * cpx + ((int)blockIdx.x >> 3);
    const int nbk = N >> 8;
    const int m0 = (swz / nbk) * 256;
    const int n0 = (swz % nbk) * 256;

    bf16* LA0 = LA;          bf16* LB0 = LB;
    bf16* LA1 = LA + 16384;  bf16* LB1 = LB + 16384;

    f32x4 acc[8][4] = {};
    bf16x8 afL[4][2], afH[4][2], bfr[4][2];

    const int NT = K >> 6, NI = K >> 7;

    stage_half(B, n0,       K, 0,  LB0,        w, l);
    stage_half(B, n0 + 128, K, 0,  LB0 + 8192, w, l);
    stage_half(A, m0,       K, 0,  LA0,        w, l);
    stage_half(A, m0 + 128, K, 0,  LA0 + 8192, w, l);
    stage_half(B, n0,       K, 64, LB1,        w, l);
    stage_half(B, n0 + 128, K, 64, LB1 + 8192, w, l);
    stage_half(A, m0,       K, 64, LA1,        w, l);
    asm volatile("s_waitcnt vmcnt(6)" ::: "memory");
    BAR();

    for (int i = 0; i < NI; ++i) {
        const int kS1 = (2 * i + 1) << 6;
        const int t2 = 2 * i + 2, t3 = 2 * i + 3;
        const int kS2 = ((t2 < NT) ? t2 : NT - 1) << 6;
        const int kS3 = ((t3 < NT) ? t3 : NT - 1) << 6;

        RDA(afL, LA0, 0);
        if (wn < 2) { RDB2(0, LB0); RDB2(2, LB0); } else { RDB2(0, LB0); }
        stage_half(A, m0 + 128, K, kS1, LA1 + 8192, w, l);
        BAR();
        MM(0, afL, 0);
        BAR();
        if (wn >= 2) { RDB2(2, LB0); }
        stage_half(B, n0, K, kS2, LB0, w, l);
        BAR();
        MM(0, afL, 2);
        BAR();
        RDA(afH, LA0, 4);
        stage_half(B, n0 + 128, K, kS2, LB0 + 8192, w, l);
        BAR();
        MM(4, afH, 0);
        BAR();
        stage_half(A, m0, K, kS2, LA0, w, l);
        BAR();
        MM(4, afH, 2);
        asm volatile("s_waitcnt vmcnt(6)" ::: "memory");
        BAR();
        RDA(afL, LA1, 0);
        if (wn < 2) { RDB2(0, LB1); RDB2(2, LB1); } else { RDB2(0, LB1); }
        stage_half(A, m0 + 128, K, kS2, LA0 + 8192, w, l);
        BAR();
        MM(0, afL, 0);
        BAR();
        if (wn >= 2) { RDB2(2, LB1); }
        stage_half(B, n0, K, kS3, LB1, w, l);
        BAR();
        MM(0, afL, 2);
        BAR();
        RDA(afH, LA1, 4);
        stage_half(B, n0 + 128, K, kS3, LB1 + 8192, w, l);
        BAR();
        MM(4, afH, 0);
        BAR();
        stage_half(A, m0, K, kS3, LA1, w, l);
        BAR();
        MM(4, afH, 2);
        asm volatile("s_waitcnt vmcnt(6)" ::: "memory");
        BAR();
    }

    asm volatile("s_waitcnt vmcnt(0)" ::: "memory");

    if (EPI == 0) {
#pragma unroll
        for (int m = 0; m < 8; ++m)
#pragma unroll
            for (int r = 0; r < 4; ++r) {
                size_t row = (size_t)(m0 + rA + m * 16 + lk * 4 + r);
                bf16* dst = C + row * N + n0 + rB;
#pragma unroll
                for (int n = 0; n < 4; ++n) dst[n * 16 + lrow] = (bf16)acc[m][n][r];
            }
    } else {
#pragma unroll
        for (int m = 0; m < 8; ++m)
#pragma unroll
            for (int r = 0; r < 4; ++r) {
                int row = m0 + rA + m * 16 + lk * 4 + r;
                int p = row & 4095, bb2 = row >> 12;
                if (p < 4000) {
                    float* dst = Cf + ((size_t)bb2 * 4000 + p) * 1024 + n0 + rB;
#pragma unroll
                    for (int n = 0; n < 4; ++n)
                        dst[n * 16 + lrow] = acc[m][n][r] + bias[n0 + rB + n * 16 + lrow];
                }
            }
    }
}

// ---------------- fused block attention + relative-position bias ----------------
// 16-wave redesign: 1024 threads, each wave owns 16 query rows (i0 = w*16).
// Halves every per-wave register array vs the 8-wave/32-row version (aq 16,
// o 32, s 16, wacc 20, stats 8 ~= 110 regs) so the forced 128-VGPR cap fits
// WITHOUT spill (rounds 4-13 all spilled ~60 regs -> scratch traffic + 1
// block/CU). 4 waves/EU doubles latency hiding. Per-jt staged K/V (barriers
// 2/jt, T14-lite prefetch). W-band narrows to 80 cols (5 ct-tiles); the
// validated ds_permute skew push/consume bijection carries over (bcc in
// [0,78], pk[2] high half unused). LDS 72,704 B.
__global__ __launch_bounds__(1024, 1) void attn_kernel(const bf16* __restrict__ qkv,
                                                       const bf16* __restrict__ relw,
                                                       bf16* __restrict__ ao) {
    int bb = blockIdx.x;
    int h = bb & 7, blkn = (bb >> 3) & 15, b = bb >> 7;
    const int t = threadIdx.x, w = t >> 6, l = t & 63, lrow = l & 15, lk = l >> 4;
    size_t qrow0 = (size_t)(b * 4096 + blkn * 256);
    __shared__ __align__(16) bf16 Ks[64 * 136];      // 17408 B
    __shared__ __align__(16) bf16 Vt[128 * 72];      // 18432 B
    __shared__ __align__(16) bf16 Ps[16][16 * 72];   // 36864 B  (total 72704)

    const int i0 = w * 16;
    const bool last = (blkn == 15);
    const int srow = t >> 4, sc8 = t & 15;           // srow in [0,64): one chunk/thread

    // ---- prologue: stage K/V tile 0 (one 16B chunk per thread) ----
    {
        bf16x8 kv = *(const bf16x8*)(qkv + (qrow0 + srow) * 3072 + 1024 + h * 128 + sc8 * 8);
        *(bf16x8*)&Ks[srow * 136 + sc8 * 8] = kv;
        bf16x8 vv = *(const bf16x8*)(qkv + (qrow0 + srow) * 3072 + 2048 + h * 128 + sc8 * 8);
        int jsw = srow ^ ((sc8 & 7) << 3);           // XOR key = (d>>3)&7 = sc8&7
#pragma unroll
        for (int e = 0; e < 8; ++e)
            Vt[(sc8 * 8 + e) * 72 + jsw] = vv[e];
    }

    bf16x8 aq[4];
#pragma unroll
    for (int ks = 0; ks < 4; ++ks)
        aq[ks] = *(const bf16x8*)(qkv + (qrow0 + i0 + lrow) * 3072 +
                                  h * 128 + ks * 32 + lk * 8);

    f32x4 o[8] = {};
    float mrun[4], lrun[4];
#pragma unroll
    for (int r = 0; r < 4; ++r) { mrun[r] = NEGBIG; lrun[r] = 0.f; }

    __syncthreads();

    const int g0 = lk * 4 + 63 - lrow;
    bf16* ps = &Ps[w][0];

    for (int jt = 0; jt < 4; ++jt) {
        // S = Q K^T (16 x 64 per wave)
        f32x4 s[4] = {};
        __builtin_amdgcn_s_setprio(1);
#pragma unroll
        for (int nt = 0; nt < 4; ++nt)
#pragma unroll
            for (int ks = 0; ks < 4; ++ks) {
                bf16x8 bk = *(const bf16x8*)&Ks[(nt * 16 + lrow) * 136 + ks * 32 + lk * 8];
                s[nt] = MFMA16(aq[ks], bk, s[nt]);
            }
        __builtin_amdgcn_s_setprio(0);

        // W-band: W[i][c] = q_i . relw[c], c in [cbase, cbase+80)
        const int cbase = i0 - jt * 64 + 192;        // in [0, 432]
        f32x4 wacc[5] = {};
        __builtin_amdgcn_s_setprio(1);
#pragma unroll
        for (int ks = 0; ks < 4; ++ks)
#pragma unroll
            for (int ct = 0; ct < 5; ++ct) {
                bf16x8 br = *(const bf16x8*)(relw + (size_t)(cbase + ct * 16 + lrow) * 128 +
                                             ks * 32 + lk * 8);
                wacc[ct] = MFMA16(aq[ks], br, wacc[ct]);
            }
        __builtin_amdgcn_s_setprio(0);

        // in-register skew gather via packed ds_permute pushes + bias add + mask
#pragma unroll
        for (int r = 0; r < 4; ++r) {
            const int Kb = g0 + r;
            const int dst = ((l & 48) | (Kb & 15)) << 2;
            unsigned pk[3];
#pragma unroll
            for (int P = 0; P < 3; ++P) {
                unsigned lo = (unsigned)__builtin_bit_cast(unsigned short,
                                    (bf16)wacc[2 * P][r]);
                unsigned hi = (2 * P + 1 < 5)
                                  ? (unsigned)__builtin_bit_cast(unsigned short,
                                        (bf16)wacc[2 * P + 1][r])
                                  : 0u;
                pk[P] = (unsigned)__builtin_amdgcn_ds_permute(dst, (int)((hi << 16) | lo));
            }
#pragma unroll
            for (int nt = 0; nt < 4; ++nt) {
                int bcc = Kb - 16 * nt;                       // in [0, 78]
                unsigned rec = (bcc < 32) ? pk[0] : (bcc < 64) ? pk[1] : pk[2];
                unsigned b16v = ((bcc >> 4) & 1) ? (rec >> 16) : (rec & 0xffffu);
                float wvf = __builtin_bit_cast(float, b16v << 16);
                float xv = (s[nt][r] + wvf) * SCALE;
                if (last && (i0 + lk * 4 + r >= 160 ||
                             jt * 64 + nt * 16 + lrow >= 160))
                    xv = NEGBIG;
                s[nt][r] = xv;
            }
        }

        // online softmax (row stats across the 16-lane col group)
#pragma unroll
        for (int r = 0; r < 4; ++r) {
            float mx = fmaxf(fmaxf(s[0][r], s[1][r]), fmaxf(s[2][r], s[3][r]));
#pragma unroll
            for (int d = 1; d < 16; d <<= 1) mx = fmaxf(mx, __shfl_xor(mx, d));
            float mold = mrun[r];
            float mn = fmaxf(mold, mx);
            float corr = __expf(mold - mn);
            mrun[r] = mn;
            float rs = 0.f;
#pragma unroll
            for (int nt = 0; nt < 4; ++nt) {
                float e = __expf(s[nt][r] - mn);
                s[nt][r] = e; rs += e;
            }
#pragma unroll
            for (int d = 1; d < 16; d <<= 1) rs += __shfl_xor(rs, d);
            lrun[r] = lrun[r] * corr + rs;
#pragma unroll
            for (int dt = 0; dt < 8; ++dt) o[dt][r] *= corr;
        }

        // O += P @ V through the per-wave 16x72 Ps buffer
#pragma unroll
        for (int nt = 0; nt < 4; ++nt)
#pragma unroll
            for (int r = 0; r < 4; ++r)
                ps[(lk * 4 + r) * 72 + nt * 16 + lrow] = (bf16)s[nt][r];
        __builtin_amdgcn_s_setprio(1);
#pragma unroll
        for (int pks = 0; pks < 2; ++pks) {
            bf16x8 ap = *(const bf16x8*)&ps[lrow * 72 + pks * 32 + lk * 8];
#pragma unroll
            for (int dt = 0; dt < 8; ++dt) {
                int d = dt * 16 + lrow;
                int jx = (pks * 32 + lk * 8) ^ (((d >> 3) & 7) << 3);
                bf16x8 bv = *(const bf16x8*)&Vt[d * 72 + jx];
                o[dt] = MFMA16(ap, bv, o[dt]);
            }
        }
        __builtin_amdgcn_s_setprio(0);

        // T14-lite: issue next tile's loads, barrier, write, barrier
        bf16x8 kreg, vreg;
        if (jt < 3) {
            int row = (jt + 1) * 64 + srow;
            kreg = *(const bf16x8*)(qkv + (qrow0 + row) * 3072 + 1024 + h * 128 + sc8 * 8);
            vreg = *(const bf16x8*)(qkv + (qrow0 + row) * 3072 + 2048 + h * 128 + sc8 * 8);
        }
        __syncthreads();                 // all waves done reading Ks/Vt of jt
        if (jt < 3) {
            *(bf16x8*)&Ks[srow * 136 + sc8 * 8] = kreg;
            int jsw = srow ^ ((sc8 & 7) << 3);
#pragma unroll
            for (int e = 0; e < 8; ++e)
                Vt[(sc8 * 8 + e) * 72 + jsw] = vreg[e];
        }
        __syncthreads();                 // next tile staged
    }

    // normalize + store (layout [row][h*128+d] for the output GEMM)
#pragma unroll
    for (int r = 0; r < 4; ++r) {
        float inv = 1.0f / lrun[r];
        size_t arow = qrow0 + i0 + lk * 4 + r;
        bf16* dst = ao + arow * 1024 + h * 128;
#pragma unroll
        for (int dt = 0; dt < 8; ++dt)
            dst[dt * 16 + lrow] = (bf16)(o[dt][r] * inv);
    }
}

// ---------------- host ----------------
extern "C" void kernel_launch(void* const* d_in, const int* in_sizes, int n_in,
                              void* d_out, int out_size, void* d_ws, size_t ws_size,
                              hipStream_t stream) {
    const float* x   = (const float*)d_in[0];
    const float* lnw = (const float*)d_in[1];
    const float* lnb = (const float*)d_in[2];
    const float* Wq  = (const float*)d_in[3];
    const float* Wkv = (const float*)d_in[4];
    const float* Wo  = (const float*)d_in[5];
    const float* bo  = (const float*)d_in[6];
    const float* rel = (const float*)d_in[7];

    const size_t OFF_XN   = 0;                          // 134,217,728 B (also AO)
    const size_t OFF_QKV  = OFF_XN + 134217728ULL;      // 402,653,184 B
    const size_t OFF_WCAT = OFF_QKV + 402653184ULL;     //   6,291,456 B
    const size_t OFF_WO   = OFF_WCAT + 6291456ULL;      //   2,097,152 B
    const size_t OFF_RELW = OFF_WO + 2097152ULL;        //     131,072 B
    const size_t NEED     = OFF_RELW + 131072ULL;       // ~520 MiB
    if (ws_size < NEED) return;   // diagnostic: will fail validation loudly

    char* ws = (char*)d_ws;
    bf16* xn   = (bf16*)(ws + OFF_XN);
    bf16* qkv  = (bf16*)(ws + OFF_QKV);
    bf16* wcat = (bf16*)(ws + OFF_WCAT);
    bf16* wo   = (bf16*)(ws + OFF_WO);
    bf16* relw = (bf16*)(ws + OFF_RELW);
    bf16* ao   = xn;                 // reuse: xn dead after qkv GEMM
    float* out = (float*)d_out;

    cvt_bf16<<<1024, 256, 0, stream>>>(Wq, wcat, 1048576);
    cvt_bf16<<<2048, 256, 0, stream>>>(Wkv, wcat + 1048576, 2097152);
    cvt_bf16<<<1024, 256, 0, stream>>>(Wo, wo, 1048576);
    cvt_bf16<<<64, 256, 0, stream>>>(rel + 257 * 128, relw, 65536);
    ln_kernel<<<65536, 256, 0, stream>>>(x, lnw, lnb, xn);
    gemm256<0><<<3072, 512, 0, stream>>>(xn, wcat, qkv, nullptr, nullptr, 65536, 3072, 1024);
    attn_kernel<<<2048, 1024, 0, stream>>>(qkv, relw, ao);
    gemm256<1><<<1024, 512, 0, stream>>>(ao, wo, nullptr, out, bo, 65536, 1024, 1024);
}

// Round 15
// 1185.621 us; speedup vs baseline: 1.1573x; 1.1573x over previous
//
#include <hip/hip_runtime.h>

typedef __bf16 bf16;
typedef __bf16 bf16x8 __attribute__((ext_vector_type(8)));
typedef float f32x4 __attribute__((ext_vector_type(4)));

#define MFMA16(A,B,C) __builtin_amdgcn_mfma_f32_16x16x32_bf16(A,B,C,0,0,0)
#define SCALE 0.08838834764831843f
#define NEGBIG (-1e30f)

#define AS1(p) ((__attribute__((address_space(1))) void*)(p))
#define AS3(p) ((__attribute__((address_space(3))) void*)(p))

#define BAR() do { asm volatile("" ::: "memory"); __builtin_amdgcn_s_barrier(); asm volatile("" ::: "memory"); } while (0)

// ---------------- f32 -> bf16 convert ----------------
__global__ void cvt_bf16(const float* __restrict__ src, bf16* __restrict__ dst, int n) {
    int i = (blockIdx.x * 256 + threadIdx.x) * 4;
    if (i < n) {
        float4 v = *(const float4*)(src + i);
        dst[i + 0] = (bf16)v.x; dst[i + 1] = (bf16)v.y;
        dst[i + 2] = (bf16)v.z; dst[i + 3] = (bf16)v.w;
    }
}

// ---------------- LayerNorm + pad to 4096 + bf16 ----------------
__global__ __launch_bounds__(256) void ln_kernel(const float* __restrict__ x,
                                                 const float* __restrict__ w,
                                                 const float* __restrict__ b,
                                                 bf16* __restrict__ xn) {
    int row = blockIdx.x;            // 0..65535  (b*4096 + p)
    int bb = row >> 12, p = row & 4095;
    int t = threadIdx.x;
    bf16* out = xn + ((size_t)row << 10);
    if (p >= 4000) {                 // padded row -> zeros
        uint2 z; z.x = 0u; z.y = 0u;
        *(uint2*)(out + t * 4) = z;
        return;
    }
    float4 v = *(const float4*)(x + (((size_t)bb * 4000 + p) << 10) + t * 4);
    float s = v.x + v.y + v.z + v.w;
    float s2 = v.x * v.x + v.y * v.y + v.z * v.z + v.w * v.w;
#pragma unroll
    for (int m = 1; m < 64; m <<= 1) { s += __shfl_xor(s, m); s2 += __shfl_xor(s2, m); }
    __shared__ float red[8];
    int wv = t >> 6, l = t & 63;
    if (l == 0) { red[wv] = s; red[4 + wv] = s2; }
    __syncthreads();
    s = red[0] + red[1] + red[2] + red[3];
    s2 = red[4] + red[5] + red[6] + red[7];
    float mu = s * (1.f / 1024.f);
    float var = s2 * (1.f / 1024.f) - mu * mu;
    float inv = rsqrtf(var + 1e-5f);
    float4 wv4 = *(const float4*)(w + t * 4);
    float4 bv4 = *(const float4*)(b + t * 4);
    union { bf16 h[4]; uint2 u; } o;
    o.h[0] = (bf16)((v.x - mu) * inv * wv4.x + bv4.x);
    o.h[1] = (bf16)((v.y - mu) * inv * wv4.y + bv4.y);
    o.h[2] = (bf16)((v.z - mu) * inv * wv4.z + bv4.z);
    o.h[3] = (bf16)((v.w - mu) * inv * wv4.w + bv4.w);
    *(uint2*)(out + t * 4) = o.u;
}

// ================= 256x256 8-phase GEMM (round-6 exact: 460 us qkv) ========
// C[M][N] = A[M][K] * B[N][K]^T, bf16 in. 512 thr = 8 waves (2M x 4N),
// BK=64, per-tile blocks, vmcnt(6) at P4/P8, 3-bit XOR swizzle (conflicts==0).
// EPI=0: bf16 C.  EPI=1: f32 out with row remap (4096-pad -> 4000) + bias.

__device__ __forceinline__ void stage_half(const bf16* __restrict__ src, int srow, int K,
                                           int kofs, bf16* ldsb, int w, int l) {
#pragma unroll
    for (int r = 0; r < 2; ++r) {
        int rh = (r * 8 + w) * 8 + (l >> 3);          // row within 128-row half
        int chunk = (l & 7) ^ (rh & 7);               // inverse 3-bit swizzle on source
        __builtin_amdgcn_global_load_lds(AS1(src + (size_t)(srow + rh) * K + kofs + chunk * 8),
                                         AS3(ldsb + (r * 8 + w) * 512), 16, 0, 0);
    }
}

__device__ __forceinline__ bf16x8 fragLD(const bf16* base, int row, int ks, int lk) {
    int ch = ((ks * 4 + lk) ^ (row & 7)) * 8;
    return *(const bf16x8*)(base + row * 64 + ch);
}

#define RDA(AF, base, mofs) \
    _Pragma("unroll") for (int m = 0; m < 4; ++m) \
    _Pragma("unroll") for (int ks = 0; ks < 2; ++ks) \
        AF[m][ks] = fragLD(base, rA + (mofs + m) * 16 + lrow, ks, lk);

#define RDB2(nb, base) \
    _Pragma("unroll") for (int n = 0; n < 2; ++n) \
    _Pragma("unroll") for (int ks = 0; ks < 2; ++ks) \
        bfr[(nb) + n][ks] = fragLD(base, rB + ((nb) + n) * 16 + lrow, ks, lk);

#define MM(mb, AF, nb) do { \
    __builtin_amdgcn_s_setprio(1); \
    _Pragma("unroll") for (int m = 0; m < 4; ++m) \
    _Pragma("unroll") for (int n = 0; n < 2; ++n) \
    _Pragma("unroll") for (int ks = 0; ks < 2; ++ks) \
        acc[(mb) + m][(nb) + n] = MFMA16(AF[m][ks], bfr[(nb) + n][ks], acc[(mb) + m][(nb) + n]); \
    __builtin_amdgcn_s_setprio(0); } while (0)

template <int EPI>
__global__ __launch_bounds__(512, 2) void gemm256(const bf16* __restrict__ A,
                                                  const bf16* __restrict__ B,
                                                  bf16* __restrict__ C,
                                                  float* __restrict__ Cf,
                                                  const float* __restrict__ bias,
                                                  int M, int N, int K) {
    __shared__ __align__(16) bf16 LA[2 * 16384];
    __shared__ __align__(16) bf16 LB[2 * 16384];
    const int t = threadIdx.x;
    const int w = t >> 6, l = t & 63;
    const int lrow = l & 15, lk = l >> 4;
    const int wrM = w >> 2, wn = w & 3;
    const int rA = wrM * 128, rB = wn * 64;

    const int nwg = gridDim.x, cpx = nwg >> 3;
    const int swz = ((int)blockIdx.x & 7) * cpx + ((int)blockIdx.x >> 3);
    const int nbk = N >> 8;
    const int m0 = (swz / nbk) * 256;
    const int n0 = (swz % nbk) * 256;

    bf16* LA0 = LA;          bf16* LB0 = LB;
    bf16* LA1 = LA + 16384;  bf16* LB1 = LB + 16384;

    f32x4 acc[8][4] = {};
    bf16x8 afL[4][2], afH[4][2], bfr[4][2];

    const int NT = K >> 6, NI = K >> 7;

    stage_half(B, n0,       K, 0,  LB0,        w, l);
    stage_half(B, n0 + 128, K, 0,  LB0 + 8192, w, l);
    stage_half(A, m0,       K, 0,  LA0,        w, l);
    stage_half(A, m0 + 128, K, 0,  LA0 + 8192, w, l);
    stage_half(B, n0,       K, 64, LB1,        w, l);
    stage_half(B, n0 + 128, K, 64, LB1 + 8192, w, l);
    stage_half(A, m0,       K, 64, LA1,        w, l);
    asm volatile("s_waitcnt vmcnt(6)" ::: "memory");
    BAR();

    for (int i = 0; i < NI; ++i) {
        const int kS1 = (2 * i + 1) << 6;
        const int t2 = 2 * i + 2, t3 = 2 * i + 3;
        const int kS2 = ((t2 < NT) ? t2 : NT - 1) << 6;
        const int kS3 = ((t3 < NT) ? t3 : NT - 1) << 6;

        RDA(afL, LA0, 0);
        if (wn < 2) { RDB2(0, LB0); RDB2(2, LB0); } else { RDB2(0, LB0); }
        stage_half(A, m0 + 128, K, kS1, LA1 + 8192, w, l);
        BAR();
        MM(0, afL, 0);
        BAR();
        if (wn >= 2) { RDB2(2, LB0); }
        stage_half(B, n0, K, kS2, LB0, w, l);
        BAR();
        MM(0, afL, 2);
        BAR();
        RDA(afH, LA0, 4);
        stage_half(B, n0 + 128, K, kS2, LB0 + 8192, w, l);
        BAR();
        MM(4, afH, 0);
        BAR();
        stage_half(A, m0, K, kS2, LA0, w, l);
        BAR();
        MM(4, afH, 2);
        asm volatile("s_waitcnt vmcnt(6)" ::: "memory");
        BAR();
        RDA(afL, LA1, 0);
        if (wn < 2) { RDB2(0, LB1); RDB2(2, LB1); } else { RDB2(0, LB1); }
        stage_half(A, m0 + 128, K, kS2, LA0 + 8192, w, l);
        BAR();
        MM(0, afL, 0);
        BAR();
        if (wn >= 2) { RDB2(2, LB1); }
        stage_half(B, n0, K, kS3, LB1, w, l);
        BAR();
        MM(0, afL, 2);
        BAR();
        RDA(afH, LA1, 4);
        stage_half(B, n0 + 128, K, kS3, LB1 + 8192, w, l);
        BAR();
        MM(4, afH, 0);
        BAR();
        stage_half(A, m0, K, kS3, LA1, w, l);
        BAR();
        MM(4, afH, 2);
        asm volatile("s_waitcnt vmcnt(6)" ::: "memory");
        BAR();
    }

    asm volatile("s_waitcnt vmcnt(0)" ::: "memory");

    if (EPI == 0) {
#pragma unroll
        for (int m = 0; m < 8; ++m)
#pragma unroll
            for (int r = 0; r < 4; ++r) {
                size_t row = (size_t)(m0 + rA + m * 16 + lk * 4 + r);
                bf16* dst = C + row * N + n0 + rB;
#pragma unroll
                for (int n = 0; n < 4; ++n) dst[n * 16 + lrow] = (bf16)acc[m][n][r];
            }
    } else {
#pragma unroll
        for (int m = 0; m < 8; ++m)
#pragma unroll
            for (int r = 0; r < 4; ++r) {
                int row = m0 + rA + m * 16 + lk * 4 + r;
                int p = row & 4095, bb2 = row >> 12;
                if (p < 4000) {
                    float* dst = Cf + ((size_t)bb2 * 4000 + p) * 1024 + n0 + rB;
#pragma unroll
                    for (int n = 0; n < 4; ++n)
                        dst[n * 16 + lrow] = acc[m][n][r] + bias[n0 + rB + n * 16 + lrow];
                }
            }
    }
}

// ---------------- fused block attention + relative-position bias ----------------
// Round-11 kernel (best measured: total 1041.6) with ONE delta: the W-band
// compute+gather is mt-SPLIT — wacc[6] (24 VGPRs) per mt instead of wacc[2][6]
// (48 VGPRs) live across the whole phase, with sched_barrier(0) pinning the
// two halves apart so the scheduler can't re-fuse them. Cuts the ~60-reg
// spill (WRITE_SIZE evidence, rounds 4/9/12) by ~24 regs. No math change.
__global__ __launch_bounds__(512, 1) void attn_kernel(const bf16* __restrict__ qkv,
                                                      const bf16* __restrict__ relw,
                                                      bf16* __restrict__ ao) {
    int bb = blockIdx.x;
    int h = bb & 7, blkn = (bb >> 3) & 15, b = bb >> 7;
    const int t = threadIdx.x, w = t >> 6, l = t & 63, lrow = l & 15, lk = l >> 4;
    size_t qrow0 = (size_t)(b * 4096 + blkn * 256);
    __shared__ __align__(16) bf16 Ks[256 * 136];     // 69632 B
    __shared__ __align__(16) bf16 Vt[128 * 264];     // 67584 B
    __shared__ __align__(16) bf16 Ps[8][16 * 72];    // 18432 B   (total 155648)

    const int i0 = w * 32;
    const bool last = (blkn == 15);

    // ---- stage ALL of K and V for head h (once; only barrier below) ----
#pragma unroll
    for (int q = 0; q < 8; ++q) {
        int idx = q * 512 + t;
        int row = idx >> 4, c8 = idx & 15;
        bf16x8 kv = *(const bf16x8*)(qkv + (qrow0 + row) * 3072 + 1024 + h * 128 + c8 * 8);
        *(bf16x8*)&Ks[row * 136 + c8 * 8] = kv;
    }
#pragma unroll
    for (int q = 0; q < 8; ++q) {
        int idx = q * 512 + t;
        int row = idx >> 4, c8 = idx & 15;           // row = j, c8 = d-chunk
        bf16x8 vv = *(const bf16x8*)(qkv + (qrow0 + row) * 3072 + 2048 + h * 128 + c8 * 8);
        int jsw = row ^ ((c8 & 7) << 3);             // XOR bank swizzle on j
#pragma unroll
        for (int e = 0; e < 8; ++e)
            Vt[(c8 * 8 + e) * 264 + jsw] = vv[e];
    }

    bf16x8 aq[2][4];
#pragma unroll
    for (int mt = 0; mt < 2; ++mt)
#pragma unroll
        for (int ks = 0; ks < 4; ++ks)
            aq[mt][ks] = *(const bf16x8*)(qkv + (qrow0 + i0 + mt * 16 + lrow) * 3072 +
                                          h * 128 + ks * 32 + lk * 8);

    f32x4 o[2][8] = {};
    float mrun[2][4], lrun[2][4];
#pragma unroll
    for (int mt = 0; mt < 2; ++mt)
#pragma unroll
        for (int r = 0; r < 4; ++r) { mrun[mt][r] = NEGBIG; lrun[mt][r] = 0.f; }

    __syncthreads();

    const int g0 = lk * 4 + 63 - lrow;
    bf16* ps = &Ps[w][0];

    for (int jt = 0; jt < 4; ++jt) {
        // S = Q K^T (32 x 64 per wave)
        f32x4 s[2][4] = {};
        __builtin_amdgcn_s_setprio(1);
#pragma unroll
        for (int nt = 0; nt < 4; ++nt)
#pragma unroll
            for (int ks = 0; ks < 4; ++ks) {
                bf16x8 bk = *(const bf16x8*)&Ks[(jt * 64 + nt * 16 + lrow) * 136 +
                                                ks * 32 + lk * 8];
                s[0][nt] = MFMA16(aq[0][ks], bk, s[0][nt]);
                s[1][nt] = MFMA16(aq[1][ks], bk, s[1][nt]);
            }
        __builtin_amdgcn_s_setprio(0);

        // W-band + skew gather, mt-SPLIT (24 live wacc regs instead of 48)
        const int cbase = i0 - jt * 64 + 192;        // in [0, 416]
#pragma unroll
        for (int mt = 0; mt < 2; ++mt) {
            f32x4 wacc[6] = {};
            __builtin_amdgcn_s_setprio(1);
#pragma unroll
            for (int ks = 0; ks < 4; ++ks)
#pragma unroll
                for (int ct = 0; ct < 6; ++ct) {
                    bf16x8 br = *(const bf16x8*)(relw +
                                    (size_t)(cbase + ct * 16 + lrow) * 128 +
                                    ks * 32 + lk * 8);
                    wacc[ct] = MFMA16(aq[mt][ks], br, wacc[ct]);
                }
            __builtin_amdgcn_s_setprio(0);

#pragma unroll
            for (int r = 0; r < 4; ++r) {
                const int Kb = g0 + mt * 16 + r;
                const int dst = ((l & 48) | (Kb & 15)) << 2;
                unsigned pk[3];
#pragma unroll
                for (int P = 0; P < 3; ++P) {
                    unsigned lo = (unsigned)__builtin_bit_cast(unsigned short,
                                        (bf16)wacc[2 * P][r]);
                    unsigned hi = (unsigned)__builtin_bit_cast(unsigned short,
                                        (bf16)wacc[2 * P + 1][r]);
                    pk[P] = (unsigned)__builtin_amdgcn_ds_permute(dst, (int)((hi << 16) | lo));
                }
#pragma unroll
                for (int nt = 0; nt < 4; ++nt) {
                    int bcc = Kb - 16 * nt;                       // in [0, 94]
                    unsigned rec = (bcc < 32) ? pk[0] : (bcc < 64) ? pk[1] : pk[2];
                    unsigned b16v = ((bcc >> 4) & 1) ? (rec >> 16) : (rec & 0xffffu);
                    float wvf = __builtin_bit_cast(float, b16v << 16);
                    float xv = (s[mt][nt][r] + wvf) * SCALE;
                    if (last && (i0 + mt * 16 + lk * 4 + r >= 160 ||
                                 jt * 64 + nt * 16 + lrow >= 160))
                        xv = NEGBIG;
                    s[mt][nt][r] = xv;
                }
            }
            __builtin_amdgcn_sched_barrier(0);       // keep the two mt halves apart
        }

        // online softmax (row stats across the 16-lane col group)
#pragma unroll
        for (int mt = 0; mt < 2; ++mt)
#pragma unroll
            for (int r = 0; r < 4; ++r) {
                float mx = fmaxf(fmaxf(s[mt][0][r], s[mt][1][r]),
                                 fmaxf(s[mt][2][r], s[mt][3][r]));
#pragma unroll
                for (int d = 1; d < 16; d <<= 1) mx = fmaxf(mx, __shfl_xor(mx, d));
                float mold = mrun[mt][r];
                float mn = fmaxf(mold, mx);
                float corr = __expf(mold - mn);
                mrun[mt][r] = mn;
                float rs = 0.f;
#pragma unroll
                for (int nt = 0; nt < 4; ++nt) {
                    float e = __expf(s[mt][nt][r] - mn);
                    s[mt][nt][r] = e; rs += e;
                }
#pragma unroll
                for (int d = 1; d < 16; d <<= 1) rs += __shfl_xor(rs, d);
                lrun[mt][r] = lrun[mt][r] * corr + rs;
#pragma unroll
                for (int dt = 0; dt < 8; ++dt) o[mt][dt][r] *= corr;
            }

        // O += P @ V, mt-split through the per-wave 16x72 Ps buffer
#pragma unroll
        for (int mt = 0; mt < 2; ++mt) {
#pragma unroll
            for (int nt = 0; nt < 4; ++nt)
#pragma unroll
                for (int r = 0; r < 4; ++r)
                    ps[(lk * 4 + r) * 72 + nt * 16 + lrow] = (bf16)s[mt][nt][r];
            __builtin_amdgcn_s_setprio(1);
#pragma unroll
            for (int pks = 0; pks < 2; ++pks) {
                bf16x8 ap = *(const bf16x8*)&ps[lrow * 72 + pks * 32 + lk * 8];
#pragma unroll
                for (int dt = 0; dt < 8; ++dt) {
                    int d = dt * 16 + lrow;
                    int jch = ((jt * 64 + pks * 32 + lk * 8) >> 3) ^ ((d >> 3) & 7);
                    bf16x8 bv = *(const bf16x8*)&Vt[d * 264 + (jch << 3)];
                    o[mt][dt] = MFMA16(ap, bv, o[mt][dt]);
                }
            }
            __builtin_amdgcn_s_setprio(0);
        }
    }

    // normalize + store (layout [row][h*128+d] for the output GEMM)
#pragma unroll
    for (int mt = 0; mt < 2; ++mt)
#pragma unroll
        for (int r = 0; r < 4; ++r) {
            float inv = 1.0f / lrun[mt][r];
            size_t arow = qrow0 + i0 + mt * 16 + lk * 4 + r;
            bf16* dst = ao + arow * 1024 + h * 128;
#pragma unroll
            for (int dt = 0; dt < 8; ++dt)
                dst[dt * 16 + lrow] = (bf16)(o[mt][dt][r] * inv);
        }
}

// ---------------- host ----------------
extern "C" void kernel_launch(void* const* d_in, const int* in_sizes, int n_in,
                              void* d_out, int out_size, void* d_ws, size_t ws_size,
                              hipStream_t stream) {
    const float* x   = (const float*)d_in[0];
    const float* lnw = (const float*)d_in[1];
    const float* lnb = (const float*)d_in[2];
    const float* Wq  = (const float*)d_in[3];
    const float* Wkv = (const float*)d_in[4];
    const float* Wo  = (const float*)d_in[5];
    const float* bo  = (const float*)d_in[6];
    const float* rel = (const float*)d_in[7];

    const size_t OFF_XN   = 0;                          // 134,217,728 B (also AO)
    const size_t OFF_QKV  = OFF_XN + 134217728ULL;      // 402,653,184 B
    const size_t OFF_WCAT = OFF_QKV + 402653184ULL;     //   6,291,456 B
    const size_t OFF_WO   = OFF_WCAT + 6291456ULL;      //   2,097,152 B
    const size_t OFF_RELW = OFF_WO + 2097152ULL;        //     131,072 B
    const size_t NEED     = OFF_RELW + 131072ULL;       // ~520 MiB
    if (ws_size < NEED) return;   // diagnostic: will fail validation loudly

    char* ws = (char*)d_ws;
    bf16* xn   = (bf16*)(ws + OFF_XN);
    bf16* qkv  = (bf16*)(ws + OFF_QKV);
    bf16* wcat = (bf16*)(ws + OFF_WCAT);
    bf16* wo   = (bf16*)(ws + OFF_WO);
    bf16* relw = (bf16*)(ws + OFF_RELW);
    bf16* ao   = xn;                 // reuse: xn dead after qkv GEMM
    float* out = (float*)d_out;

    cvt_bf16<<<1024, 256, 0, stream>>>(Wq, wcat, 1048576);
    cvt_bf16<<<2048, 256, 0, stream>>>(Wkv, wcat + 1048576, 2097152);
    cvt_bf16<<<1024, 256, 0, stream>>>(Wo, wo, 1048576);
    cvt_bf16<<<64, 256, 0, stream>>>(rel + 257 * 128, relw, 65536);
    ln_kernel<<<65536, 256, 0, stream>>>(x, lnw, lnb, xn);
    gemm256<0><<<3072, 512, 0, stream>>>(xn, wcat, qkv, nullptr, nullptr, 65536, 3072, 1024);
    attn_kernel<<<2048, 512, 0, stream>>>(qkv, relw, ao);
    gemm256<1><<<1024, 512, 0, stream>>>(ao, wo, nullptr, out, bo, 65536, 1024, 1024);
}

// Round 16
// 1001.924 us; speedup vs baseline: 1.3695x; 1.1833x over previous
//
#include <hip/hip_runtime.h>

typedef __bf16 bf16;
typedef __bf16 bf16x8 __attribute__((ext_vector_type(8)));
typedef float f32x4 __attribute__((ext_vector_type(4)));

#define MFMA16(A,B,C) __builtin_amdgcn_mfma_f32_16x16x32_bf16(A,B,C,0,0,0)
#define SCALE 0.08838834764831843f
#define NEGBIG (-1e30f)

#define AS1(p) ((__attribute__((address_space(1))) void*)(p))
#define AS3(p) ((__attribute__((address_space(3))) void*)(p))

#define BAR() do { asm volatile("" ::: "memory"); __builtin_amdgcn_s_barrier(); asm volatile("" ::: "memory"); } while (0)

// ---------------- f32 -> bf16 convert ----------------
__global__ void cvt_bf16(const float* __restrict__ src, bf16* __restrict__ dst, int n) {
    int i = (blockIdx.x * 256 + threadIdx.x) * 4;
    if (i < n) {
        float4 v = *(const float4*)(src + i);
        dst[i + 0] = (bf16)v.x; dst[i + 1] = (bf16)v.y;
        dst[i + 2] = (bf16)v.z; dst[i + 3] = (bf16)v.w;
    }
}

// ---------------- LayerNorm + pad to 4096 + bf16 ----------------
__global__ __launch_bounds__(256) void ln_kernel(const float* __restrict__ x,
                                                 const float* __restrict__ w,
                                                 const float* __restrict__ b,
                                                 bf16* __restrict__ xn) {
    int row = blockIdx.x;            // 0..65535  (b*4096 + p)
    int bb = row >> 12, p = row & 4095;
    int t = threadIdx.x;
    bf16* out = xn + ((size_t)row << 10);
    if (p >= 4000) {                 // padded row -> zeros
        uint2 z; z.x = 0u; z.y = 0u;
        *(uint2*)(out + t * 4) = z;
        return;
    }
    float4 v = *(const float4*)(x + (((size_t)bb * 4000 + p) << 10) + t * 4);
    float s = v.x + v.y + v.z + v.w;
    float s2 = v.x * v.x + v.y * v.y + v.z * v.z + v.w * v.w;
#pragma unroll
    for (int m = 1; m < 64; m <<= 1) { s += __shfl_xor(s, m); s2 += __shfl_xor(s2, m); }
    __shared__ float red[8];
    int wv = t >> 6, l = t & 63;
    if (l == 0) { red[wv] = s; red[4 + wv] = s2; }
    __syncthreads();
    s = red[0] + red[1] + red[2] + red[3];
    s2 = red[4] + red[5] + red[6] + red[7];
    float mu = s * (1.f / 1024.f);
    float var = s2 * (1.f / 1024.f) - mu * mu;
    float inv = rsqrtf(var + 1e-5f);
    float4 wv4 = *(const float4*)(w + t * 4);
    float4 bv4 = *(const float4*)(b + t * 4);
    union { bf16 h[4]; uint2 u; } o;
    o.h[0] = (bf16)((v.x - mu) * inv * wv4.x + bv4.x);
    o.h[1] = (bf16)((v.y - mu) * inv * wv4.y + bv4.y);
    o.h[2] = (bf16)((v.z - mu) * inv * wv4.z + bv4.z);
    o.h[3] = (bf16)((v.w - mu) * inv * wv4.w + bv4.w);
    *(uint2*)(out + t * 4) = o.u;
}

// ================= 256x256 8-phase GEMM (round-6 exact: 460 us qkv) ========
// C[M][N] = A[M][K] * B[N][K]^T, bf16 in. 512 thr = 8 waves (2M x 4N),
// BK=64, per-tile blocks, vmcnt(6) at P4/P8, 3-bit XOR swizzle (conflicts==0).
// EPI=0: bf16 C.  EPI=1: f32 out with row remap (4096-pad -> 4000) + bias.

__device__ __forceinline__ void stage_half(const bf16* __restrict__ src, int srow, int K,
                                           int kofs, bf16* ldsb, int w, int l) {
#pragma unroll
    for (int r = 0; r < 2; ++r) {
        int rh = (r * 8 + w) * 8 + (l >> 3);          // row within 128-row half
        int chunk = (l & 7) ^ (rh & 7);               // inverse 3-bit swizzle on source
        __builtin_amdgcn_global_load_lds(AS1(src + (size_t)(srow + rh) * K + kofs + chunk * 8),
                                         AS3(ldsb + (r * 8 + w) * 512), 16, 0, 0);
    }
}

__device__ __forceinline__ bf16x8 fragLD(const bf16* base, int row, int ks, int lk) {
    int ch = ((ks * 4 + lk) ^ (row & 7)) * 8;
    return *(const bf16x8*)(base + row * 64 + ch);
}

#define RDA(AF, base, mofs) \
    _Pragma("unroll") for (int m = 0; m < 4; ++m) \
    _Pragma("unroll") for (int ks = 0; ks < 2; ++ks) \
        AF[m][ks] = fragLD(base, rA + (mofs + m) * 16 + lrow, ks, lk);

#define RDB2(nb, base) \
    _Pragma("unroll") for (int n = 0; n < 2; ++n) \
    _Pragma("unroll") for (int ks = 0; ks < 2; ++ks) \
        bfr[(nb) + n][ks] = fragLD(base, rB + ((nb) + n) * 16 + lrow, ks, lk);

#define MM(mb, AF, nb) do { \
    __builtin_amdgcn_s_setprio(1); \
    _Pragma("unroll") for (int m = 0; m < 4; ++m) \
    _Pragma("unroll") for (int n = 0; n < 2; ++n) \
    _Pragma("unroll") for (int ks = 0; ks < 2; ++ks) \
        acc[(mb) + m][(nb) + n] = MFMA16(AF[m][ks], bfr[(nb) + n][ks], acc[(mb) + m][(nb) + n]); \
    __builtin_amdgcn_s_setprio(0); } while (0)

template <int EPI>
__global__ __launch_bounds__(512, 2) void gemm256(const bf16* __restrict__ A,
                                                  const bf16* __restrict__ B,
                                                  bf16* __restrict__ C,
                                                  float* __restrict__ Cf,
                                                  const float* __restrict__ bias,
                                                  int M, int N, int K) {
    __shared__ __align__(16) bf16 LA[2 * 16384];
    __shared__ __align__(16) bf16 LB[2 * 16384];
    const int t = threadIdx.x;
    const int w = t >> 6, l = t & 63;
    const int lrow = l & 15, lk = l >> 4;
    const int wrM = w >> 2, wn = w & 3;
    const int rA = wrM * 128, rB = wn * 64;

    const int nwg = gridDim.x, cpx = nwg >> 3;
    const int swz = ((int)blockIdx.x & 7) * cpx + ((int)blockIdx.x >> 3);
    const int nbk = N >> 8;
    const int m0 = (swz / nbk) * 256;
    const int n0 = (swz % nbk) * 256;

    bf16* LA0 = LA;          bf16* LB0 = LB;
    bf16* LA1 = LA + 16384;  bf16* LB1 = LB + 16384;

    f32x4 acc[8][4] = {};
    bf16x8 afL[4][2], afH[4][2], bfr[4][2];

    const int NT = K >> 6, NI = K >> 7;

    stage_half(B, n0,       K, 0,  LB0,        w, l);
    stage_half(B, n0 + 128, K, 0,  LB0 + 8192, w, l);
    stage_half(A, m0,       K, 0,  LA0,        w, l);
    stage_half(A, m0 + 128, K, 0,  LA0 + 8192, w, l);
    stage_half(B, n0,       K, 64, LB1,        w, l);
    stage_half(B, n0 + 128, K, 64, LB1 + 8192, w, l);
    stage_half(A, m0,       K, 64, LA1,        w, l);
    asm volatile("s_waitcnt vmcnt(6)" ::: "memory");
    BAR();

    for (int i = 0; i < NI; ++i) {
        const int kS1 = (2 * i + 1) << 6;
        const int t2 = 2 * i + 2, t3 = 2 * i + 3;
        const int kS2 = ((t2 < NT) ? t2 : NT - 1) << 6;
        const int kS3 = ((t3 < NT) ? t3 : NT - 1) << 6;

        RDA(afL, LA0, 0);
        if (wn < 2) { RDB2(0, LB0); RDB2(2, LB0); } else { RDB2(0, LB0); }
        stage_half(A, m0 + 128, K, kS1, LA1 + 8192, w, l);
        BAR();
        MM(0, afL, 0);
        BAR();
        if (wn >= 2) { RDB2(2, LB0); }
        stage_half(B, n0, K, kS2, LB0, w, l);
        BAR();
        MM(0, afL, 2);
        BAR();
        RDA(afH, LA0, 4);
        stage_half(B, n0 + 128, K, kS2, LB0 + 8192, w, l);
        BAR();
        MM(4, afH, 0);
        BAR();
        stage_half(A, m0, K, kS2, LA0, w, l);
        BAR();
        MM(4, afH, 2);
        asm volatile("s_waitcnt vmcnt(6)" ::: "memory");
        BAR();
        RDA(afL, LA1, 0);
        if (wn < 2) { RDB2(0, LB1); RDB2(2, LB1); } else { RDB2(0, LB1); }
        stage_half(A, m0 + 128, K, kS2, LA0 + 8192, w, l);
        BAR();
        MM(0, afL, 0);
        BAR();
        if (wn >= 2) { RDB2(2, LB1); }
        stage_half(B, n0, K, kS3, LB1, w, l);
        BAR();
        MM(0, afL, 2);
        BAR();
        RDA(afH, LA1, 4);
        stage_half(B, n0 + 128, K, kS3, LB1 + 8192, w, l);
        BAR();
        MM(4, afH, 0);
        BAR();
        stage_half(A, m0, K, kS3, LA1, w, l);
        BAR();
        MM(4, afH, 2);
        asm volatile("s_waitcnt vmcnt(6)" ::: "memory");
        BAR();
    }

    asm volatile("s_waitcnt vmcnt(0)" ::: "memory");

    if (EPI == 0) {
#pragma unroll
        for (int m = 0; m < 8; ++m)
#pragma unroll
            for (int r = 0; r < 4; ++r) {
                size_t row = (size_t)(m0 + rA + m * 16 + lk * 4 + r);
                bf16* dst = C + row * N + n0 + rB;
#pragma unroll
                for (int n = 0; n < 4; ++n) dst[n * 16 + lrow] = (bf16)acc[m][n][r];
            }
    } else {
#pragma unroll
        for (int m = 0; m < 8; ++m)
#pragma unroll
            for (int r = 0; r < 4; ++r) {
                int row = m0 + rA + m * 16 + lk * 4 + r;
                int p = row & 4095, bb2 = row >> 12;
                if (p < 4000) {
                    float* dst = Cf + ((size_t)bb2 * 4000 + p) * 1024 + n0 + rB;
#pragma unroll
                    for (int n = 0; n < 4; ++n)
                        dst[n * 16 + lrow] = acc[m][n][r] + bias[n0 + rB + n * 16 + lrow];
                }
            }
    }
}

// ---------------- fused block attention + relative-position bias ----------------
// Round-11 kernel (best measured: total 1041.6) with ONE delta: the W-band is
// split over CT-PAIRS, not mt. Per pair P: w2[2][2] (16 transient regs) over
// all ks with br loads SHARED across both mt (same 24 loads/jt as round-11,
// unlike round-15's mt-split which doubled them), then immediate cvt+push into
// pk[2][4][3] (24 live). Peak live wacc-state drops ~48 -> ~40 with no extra
// loads and NO sched_barrier pinning (round-15's two regression mechanisms).
__global__ __launch_bounds__(512, 1) void attn_kernel(const bf16* __restrict__ qkv,
                                                      const bf16* __restrict__ relw,
                                                      bf16* __restrict__ ao) {
    int bb = blockIdx.x;
    int h = bb & 7, blkn = (bb >> 3) & 15, b = bb >> 7;
    const int t = threadIdx.x, w = t >> 6, l = t & 63, lrow = l & 15, lk = l >> 4;
    size_t qrow0 = (size_t)(b * 4096 + blkn * 256);
    __shared__ __align__(16) bf16 Ks[256 * 136];     // 69632 B
    __shared__ __align__(16) bf16 Vt[128 * 264];     // 67584 B
    __shared__ __align__(16) bf16 Ps[8][16 * 72];    // 18432 B   (total 155648)

    const int i0 = w * 32;
    const bool last = (blkn == 15);

    // ---- stage ALL of K and V for head h (once; only barrier below) ----
#pragma unroll
    for (int q = 0; q < 8; ++q) {
        int idx = q * 512 + t;
        int row = idx >> 4, c8 = idx & 15;
        bf16x8 kv = *(const bf16x8*)(qkv + (qrow0 + row) * 3072 + 1024 + h * 128 + c8 * 8);
        *(bf16x8*)&Ks[row * 136 + c8 * 8] = kv;
    }
#pragma unroll
    for (int q = 0; q < 8; ++q) {
        int idx = q * 512 + t;
        int row = idx >> 4, c8 = idx & 15;           // row = j, c8 = d-chunk
        bf16x8 vv = *(const bf16x8*)(qkv + (qrow0 + row) * 3072 + 2048 + h * 128 + c8 * 8);
        int jsw = row ^ ((c8 & 7) << 3);             // XOR bank swizzle on j
#pragma unroll
        for (int e = 0; e < 8; ++e)
            Vt[(c8 * 8 + e) * 264 + jsw] = vv[e];
    }

    bf16x8 aq[2][4];
#pragma unroll
    for (int mt = 0; mt < 2; ++mt)
#pragma unroll
        for (int ks = 0; ks < 4; ++ks)
            aq[mt][ks] = *(const bf16x8*)(qkv + (qrow0 + i0 + mt * 16 + lrow) * 3072 +
                                          h * 128 + ks * 32 + lk * 8);

    f32x4 o[2][8] = {};
    float mrun[2][4], lrun[2][4];
#pragma unroll
    for (int mt = 0; mt < 2; ++mt)
#pragma unroll
        for (int r = 0; r < 4; ++r) { mrun[mt][r] = NEGBIG; lrun[mt][r] = 0.f; }

    __syncthreads();

    const int g0 = lk * 4 + 63 - lrow;
    bf16* ps = &Ps[w][0];

    for (int jt = 0; jt < 4; ++jt) {
        // S = Q K^T (32 x 64 per wave)
        f32x4 s[2][4] = {};
        __builtin_amdgcn_s_setprio(1);
#pragma unroll
        for (int nt = 0; nt < 4; ++nt)
#pragma unroll
            for (int ks = 0; ks < 4; ++ks) {
                bf16x8 bk = *(const bf16x8*)&Ks[(jt * 64 + nt * 16 + lrow) * 136 +
                                                ks * 32 + lk * 8];
                s[0][nt] = MFMA16(aq[0][ks], bk, s[0][nt]);
                s[1][nt] = MFMA16(aq[1][ks], bk, s[1][nt]);
            }
        __builtin_amdgcn_s_setprio(0);

        // W-band over ct-pairs: w2[2][2] transient, br shared across mt,
        // immediate cvt+push into pk[2][4][3]
        const int cbase = i0 - jt * 64 + 192;        // in [0, 416]
        unsigned pk[2][4][3];
#pragma unroll
        for (int P = 0; P < 3; ++P) {
            f32x4 w2[2][2] = {};
            __builtin_amdgcn_s_setprio(1);
#pragma unroll
            for (int ks = 0; ks < 4; ++ks)
#pragma unroll
                for (int cc = 0; cc < 2; ++cc) {
                    bf16x8 br = *(const bf16x8*)(relw +
                                    (size_t)(cbase + (P * 2 + cc) * 16 + lrow) * 128 +
                                    ks * 32 + lk * 8);
                    w2[0][cc] = MFMA16(aq[0][ks], br, w2[0][cc]);
                    w2[1][cc] = MFMA16(aq[1][ks], br, w2[1][cc]);
                }
            __builtin_amdgcn_s_setprio(0);
#pragma unroll
            for (int mt = 0; mt < 2; ++mt)
#pragma unroll
                for (int r = 0; r < 4; ++r) {
                    const int Kb = g0 + mt * 16 + r;
                    const int dst = ((l & 48) | (Kb & 15)) << 2;
                    unsigned lo = (unsigned)__builtin_bit_cast(unsigned short,
                                        (bf16)w2[mt][0][r]);
                    unsigned hi = (unsigned)__builtin_bit_cast(unsigned short,
                                        (bf16)w2[mt][1][r]);
                    pk[mt][r][P] = (unsigned)__builtin_amdgcn_ds_permute(
                                        dst, (int)((hi << 16) | lo));
                }
        }

        // gather + bias add + mask (static pair selection, rule-20 safe)
#pragma unroll
        for (int mt = 0; mt < 2; ++mt)
#pragma unroll
            for (int r = 0; r < 4; ++r) {
                const int Kb = g0 + mt * 16 + r;
#pragma unroll
                for (int nt = 0; nt < 4; ++nt) {
                    int bcc = Kb - 16 * nt;                       // in [0, 94]
                    unsigned rec = (bcc < 32) ? pk[mt][r][0]
                                 : (bcc < 64) ? pk[mt][r][1] : pk[mt][r][2];
                    unsigned b16v = ((bcc >> 4) & 1) ? (rec >> 16) : (rec & 0xffffu);
                    float wvf = __builtin_bit_cast(float, b16v << 16);
                    float xv = (s[mt][nt][r] + wvf) * SCALE;
                    if (last && (i0 + mt * 16 + lk * 4 + r >= 160 ||
                                 jt * 64 + nt * 16 + lrow >= 160))
                        xv = NEGBIG;
                    s[mt][nt][r] = xv;
                }
            }

        // online softmax (row stats across the 16-lane col group)
#pragma unroll
        for (int mt = 0; mt < 2; ++mt)
#pragma unroll
            for (int r = 0; r < 4; ++r) {
                float mx = fmaxf(fmaxf(s[mt][0][r], s[mt][1][r]),
                                 fmaxf(s[mt][2][r], s[mt][3][r]));
#pragma unroll
                for (int d = 1; d < 16; d <<= 1) mx = fmaxf(mx, __shfl_xor(mx, d));
                float mold = mrun[mt][r];
                float mn = fmaxf(mold, mx);
                float corr = __expf(mold - mn);
                mrun[mt][r] = mn;
                float rs = 0.f;
#pragma unroll
                for (int nt = 0; nt < 4; ++nt) {
                    float e = __expf(s[mt][nt][r] - mn);
                    s[mt][nt][r] = e; rs += e;
                }
#pragma unroll
                for (int d = 1; d < 16; d <<= 1) rs += __shfl_xor(rs, d);
                lrun[mt][r] = lrun[mt][r] * corr + rs;
#pragma unroll
                for (int dt = 0; dt < 8; ++dt) o[mt][dt][r] *= corr;
            }

        // O += P @ V, mt-split through the per-wave 16x72 Ps buffer
#pragma unroll
        for (int mt = 0; mt < 2; ++mt) {
#pragma unroll
            for (int nt = 0; nt < 4; ++nt)
#pragma unroll
                for (int r = 0; r < 4; ++r)
                    ps[(lk * 4 + r) * 72 + nt * 16 + lrow] = (bf16)s[mt][nt][r];
            __builtin_amdgcn_s_setprio(1);
#pragma unroll
            for (int pks = 0; pks < 2; ++pks) {
                bf16x8 ap = *(const bf16x8*)&ps[lrow * 72 + pks * 32 + lk * 8];
#pragma unroll
                for (int dt = 0; dt < 8; ++dt) {
                    int d = dt * 16 + lrow;
                    int jch = ((jt * 64 + pks * 32 + lk * 8) >> 3) ^ ((d >> 3) & 7);
                    bf16x8 bv = *(const bf16x8*)&Vt[d * 264 + (jch << 3)];
                    o[mt][dt] = MFMA16(ap, bv, o[mt][dt]);
                }
            }
            __builtin_amdgcn_s_setprio(0);
        }
    }

    // normalize + store (layout [row][h*128+d] for the output GEMM)
#pragma unroll
    for (int mt = 0; mt < 2; ++mt)
#pragma unroll
        for (int r = 0; r < 4; ++r) {
            float inv = 1.0f / lrun[mt][r];
            size_t arow = qrow0 + i0 + mt * 16 + lk * 4 + r;
            bf16* dst = ao + arow * 1024 + h * 128;
#pragma unroll
            for (int dt = 0; dt < 8; ++dt)
                dst[dt * 16 + lrow] = (bf16)(o[mt][dt][r] * inv);
        }
}

// ---------------- host ----------------
extern "C" void kernel_launch(void* const* d_in, const int* in_sizes, int n_in,
                              void* d_out, int out_size, void* d_ws, size_t ws_size,
                              hipStream_t stream) {
    const float* x   = (const float*)d_in[0];
    const float* lnw = (const float*)d_in[1];
    const float* lnb = (const float*)d_in[2];
    const float* Wq  = (const float*)d_in[3];
    const float* Wkv = (const float*)d_in[4];
    const float* Wo  = (const float*)d_in[5];
    const float* bo  = (const float*)d_in[6];
    const float* rel = (const float*)d_in[7];

    const size_t OFF_XN   = 0;                          // 134,217,728 B (also AO)
    const size_t OFF_QKV  = OFF_XN + 134217728ULL;      // 402,653,184 B
    const size_t OFF_WCAT = OFF_QKV + 402653184ULL;     //   6,291,456 B
    const size_t OFF_WO   = OFF_WCAT + 6291456ULL;      //   2,097,152 B
    const size_t OFF_RELW = OFF_WO + 2097152ULL;        //     131,072 B
    const size_t NEED     = OFF_RELW + 131072ULL;       // ~520 MiB
    if (ws_size < NEED) return;   // diagnostic: will fail validation loudly

    char* ws = (char*)d_ws;
    bf16* xn   = (bf16*)(ws + OFF_XN);
    bf16* qkv  = (bf16*)(ws + OFF_QKV);
    bf16* wcat = (bf16*)(ws + OFF_WCAT);
    bf16* wo   = (bf16*)(ws + OFF_WO);
    bf16* relw = (bf16*)(ws + OFF_RELW);
    bf16* ao   = xn;                 // reuse: xn dead after qkv GEMM
    float* out = (float*)d_out;

    cvt_bf16<<<1024, 256, 0, stream>>>(Wq, wcat, 1048576);
    cvt_bf16<<<2048, 256, 0, stream>>>(Wkv, wcat + 1048576, 2097152);
    cvt_bf16<<<1024, 256, 0, stream>>>(Wo, wo, 1048576);
    cvt_bf16<<<64, 256, 0, stream>>>(rel + 257 * 128, relw, 65536);
    ln_kernel<<<65536, 256, 0, stream>>>(x, lnw, lnb, xn);
    gemm256<0><<<3072, 512, 0, stream>>>(xn, wcat, qkv, nullptr, nullptr, 65536, 3072, 1024);
    attn_kernel<<<2048, 512, 0, stream>>>(qkv, relw, ao);
    gemm256<1><<<1024, 512, 0, stream>>>(ao, wo, nullptr, out, bo, 65536, 1024, 1024);
}